// Round 6
// baseline (231.410 us; speedup 1.0000x reference)
//
#include <hip/hip_runtime.h>

typedef unsigned short u16;
typedef unsigned int u32;
typedef __bf16 bf16x8 __attribute__((ext_vector_type(8)));
typedef unsigned short ushort8 __attribute__((ext_vector_type(8)));
typedef float floatx4 __attribute__((ext_vector_type(4)));
typedef u32 u32x2 __attribute__((ext_vector_type(2)));

#define S_LEN 2048
#define NH 32
#define NKV 8
#define HD_ 64
#define LDQ 3072   // qkv row stride: [q 0..2047 | k 2048..2559 | v 2560..3071]

__device__ __forceinline__ u16 f2bf(float f) {
  unsigned u = __builtin_bit_cast(unsigned, f);
  u += 0x7FFF + ((u >> 16) & 1);   // round-to-nearest-even
  return (u16)(u >> 16);
}
__device__ __forceinline__ float bf2f(u16 h) {
  unsigned u = ((unsigned)h) << 16;
  return __builtin_bit_cast(float, u);
}
__device__ __forceinline__ bf16x8 ld8(const u16* p) {
  return __builtin_bit_cast(bf16x8, *(const ushort8*)p);
}
__device__ __forceinline__ floatx4 mfma16(bf16x8 a, bf16x8 b, floatx4 c) {
  return __builtin_amdgcn_mfma_f32_16x16x32_bf16(a, b, c, 0, 0, 0);
}
// two fp32 -> packed bf16 pair (round-half-up via +0x8000, then byte-perm)
__device__ __forceinline__ u32 pk2bf(float a, float b) {
  u32 ua = __builtin_bit_cast(u32, a) + 0x8000u;
  u32 ub = __builtin_bit_cast(u32, b) + 0x8000u;
  return __builtin_amdgcn_perm(ub, ua, 0x07060302);   // [bf(a) | bf(b)<<16]
}
// async global->LDS DMA, 16B per lane. LDS dest is wave-uniform base + lane*16
// (per-lane lds ptr passed for clarity; HW uses linear lane order).
__device__ __forceinline__ void gl_lds16(const u16* g, u16* l) {
  __builtin_amdgcn_global_load_lds(
      (const __attribute__((address_space(1))) void*)g,
      (__attribute__((address_space(3))) void*)l, 16, 0, 0);
}

// ---------------- fp32 -> bf16 convert (vectorized) ----------------
__global__ void cvt_kernel(const float* __restrict__ in, u16* __restrict__ out, int n4) {
  int i = blockIdx.x * blockDim.x + threadIdx.x;
  if (i >= n4) return;
  float4 v = ((const float4*)in)[i];
  ((ushort4*)out)[i] = make_ushort4(f2bf(v.x), f2bf(v.y), f2bf(v.z), f2bf(v.w));
}

// ---------------- Double-buffered GEMM: C[M][N] = A[M][K] @ B[N][K]^T (bf16 in) ------------
// TM x TN tile, BK=64, 4 waves (2x2). r6: staging converted from reg-staged
// (global->reg->ds_write, 7 ds_write_b128 + 28 VGPR + vmcnt->ds_write serial chain per
// thread-iter) to global_load_lds width=16 DMA (guide m151: +35% at this tile size).
// Swizzled LDS layout preserved via rule #21: LINEAR LDS dest + INVERSE-SWIZZLED source.
// Every DMA issue covers 8 rows (8 lanes/row), so row&7 == lane>>3 and the source chunk
// is the lane-constant (lane&7)^(lane>>3) — a permutation WITHIN each row's 128B
// segment, so global coalescing is intact. One __syncthreads per K-iter drains the DMA
// (vmcnt) once, after the full compute phase. Tiles: QKV 128x96 (2/CU), O-proj 128x64
// (512 blocks) — r3-proven; r4's smaller tiles regressed.
template <int TM, int TN, int OUT_BF16>
__global__ __launch_bounds__(256) void gemm_db(
    const u16* __restrict__ A, const u16* __restrict__ B, void* __restrict__ C,
    int ldc, int K, int lda) {
  __shared__ __align__(16) u16 As[2][TM * 64];
  __shared__ __align__(16) u16 Bs[2][TN * 64];
  const int tid = threadIdx.x;
  const int wave = tid >> 6, lane = tid & 63;
  const int quad = lane >> 4, l16 = lane & 15;
  const int bm = blockIdx.y * TM, bn = blockIdx.x * TN;
  const int wr = (wave >> 1) * (TM / 2), wc = (wave & 1) * (TN / 2);
  constexpr int MI = TM / 32, NI = TN / 32;

  // DMA staging geometry: wave w issue j covers rows [j*32 + w*8, +8), lane>>3 = row
  // offset, lane&7 = storage chunk; source chunk = (lane&7)^(lane>>3) (inverse swizzle).
  const int lrow = lane >> 3;
  const int schunk = (lane & 7) ^ lrow;
  const u16* gA = A + (size_t)(bm + wave * 8 + lrow) * lda + schunk * 8;
  const u16* gB = B + (size_t)(bn + wave * 8 + lrow) * K + schunk * 8;

  auto stage = [&](int p, int k0) {
#pragma unroll
    for (int j = 0; j < MI; j++)
      gl_lds16(gA + (size_t)(j * 32) * lda + k0,
               &As[p][(wave * 8 + j * 32) * 64 + lane * 8]);
#pragma unroll
    for (int j = 0; j < NI; j++)
      gl_lds16(gB + (size_t)(j * 32) * K + k0,
               &Bs[p][(wave * 8 + j * 32) * 64 + lane * 8]);
  };

  floatx4 acc[MI][NI] = {};
  stage(0, 0);
  __syncthreads();                               // drains prologue DMA (vmcnt)
  int p = 0;
  for (int k0 = 0; k0 < K; k0 += 64) {
    const bool more = (k0 + 64 < K);
    if (more) stage(p ^ 1, k0 + 64);             // DMA next tile; overlaps compute below
#pragma unroll
    for (int kh = 0; kh < 2; kh++) {
      bf16x8 af[MI], bfr[NI];
#pragma unroll
      for (int mi = 0; mi < MI; mi++) {
        const int row = wr + mi * 16 + l16;
        af[mi] = ld8(&As[p][row * 64 + (((kh * 4 + quad) ^ (row & 7)) * 8)]);
      }
#pragma unroll
      for (int ni = 0; ni < NI; ni++) {
        const int row = wc + ni * 16 + l16;
        bfr[ni] = ld8(&Bs[p][row * 64 + (((kh * 4 + quad) ^ (row & 7)) * 8)]);
      }
#pragma unroll
      for (int mi = 0; mi < MI; mi++)
#pragma unroll
        for (int ni = 0; ni < NI; ni++)
          acc[mi][ni] = mfma16(af[mi], bfr[ni], acc[mi][ni]);
    }
    if (more) {
      __syncthreads();                           // one barrier per iter; drains DMA
      p ^= 1;
    }
  }

#pragma unroll
  for (int mi = 0; mi < MI; mi++)
#pragma unroll
    for (int ni = 0; ni < NI; ni++)
#pragma unroll
      for (int r = 0; r < 4; r++) {
        const int row = bm + wr + mi * 16 + quad * 4 + r;   // C/D: row=(lane>>4)*4+reg
        const int col = bn + wc + ni * 16 + l16;            //      col=lane&15
        if (OUT_BF16) ((u16*)C)[(size_t)row * ldc + col] = f2bf(acc[mi][ni][r]);
        else          ((float*)C)[(size_t)row * ldc + col] = acc[mi][ni][r];
      }
}

// ---------------- RoPE in-place on bf16, rows of `row_stride`, nheads = 1<<h_bits ----------------
__global__ void rope_kernel(u16* __restrict__ qk, const float* __restrict__ fc, int h_bits,
                            int row_stride, float scale) {
  int idx = blockIdx.x * blockDim.x + threadIdx.x;   // over S * nheads * 32 pairs
  int d = idx & 31;
  int t = idx >> 5;
  int hh = t & ((1 << h_bits) - 1);
  int s = t >> h_bits;
  float c  = fc[s * 64 + d * 2];
  float sn = fc[s * 64 + d * 2 + 1];
  size_t base = (size_t)s * row_stride + hh * 64 + d * 2;
  float x0 = bf2f(qk[base]), x1 = bf2f(qk[base + 1]);
  qk[base]     = f2bf((x0 * c - x1 * sn) * scale);
  qk[base + 1] = f2bf((x0 * sn + x1 * c) * scale);
}

// ---------------- V transpose: qkv[s][2560 + g*64+hd] -> vT[(g*64+hd)][s] ----------------
__global__ void transpose_v(const u16* __restrict__ qkv, u16* __restrict__ vT) {
  int idx = blockIdx.x * blockDim.x + threadIdx.x;   // over KV*HD*S
  int s = idx & (S_LEN - 1);
  int t = idx >> 11;                                 // g*64+hd
  vT[idx] = qkv[(size_t)s * LDQ + 2560 + t];
}

// ---------------- Flash attention (causal, GQA) — r5 structure (kept) ------------
// r2's two-phase uniform schedule + r3's conflict-free chunk-XOR stride-64 LDS +
// K/V double-buffer with ONE RAW s_barrier per iter (lgkmcnt(0) only; prefetch
// global_loads are register-destined and stay in flight across the barrier).
__global__ __launch_bounds__(256) void attn_kernel(const u16* qkv, const u16* __restrict__ vT,
                                                   u16* __restrict__ o) {
  __shared__ __align__(16) u16 Ks[2][64 * 64];   // [key][hd], chunk-XOR swizzled
  __shared__ __align__(16) u16 Vs[2][64 * 64];   // [hd][key], chunk-XOR swizzled
  __shared__ __align__(16) u16 pS[4][16 * 64];   // per-wave P^T scratch (reused A/B)
  const int h = blockIdx.x;
  const int g = h >> 2;                          // kv head
  const int tid = threadIdx.x;
  const int wave = tid >> 6, lane = tid & 63;
  const int quad = lane >> 4, l16 = lane & 15;
  const int p_ = (int)blockIdx.y;                // 0..15
  const int qtB = 31 - p_;                       // pair (p_, 31-p_): 33 iters total

  const ushort8 ones_u = {0x3F80, 0x3F80, 0x3F80, 0x3F80, 0x3F80, 0x3F80, 0x3F80, 0x3F80};
  const bf16x8 onesA = __builtin_bit_cast(bf16x8, ones_u);

  const int qrow = wave * 16 + l16;
  const int qgA = p_ * 64 + qrow, qgB = qtB * 64 + qrow;
  const size_t qoffA = (size_t)qgA * LDQ + h * HD_;
  const size_t qoffB = (size_t)qgB * LDQ + h * HD_;
  bf16x8 qfA0 = ld8(qkv + qoffA + quad * 8);     // B-frag: n=q, k=hd (pre-scaled log2e/8)
  bf16x8 qfA1 = ld8(qkv + qoffA + 32 + quad * 8);
  bf16x8 qfB0 = ld8(qkv + qoffB + quad * 8);
  bf16x8 qfB1 = ld8(qkv + qoffB + 32 + quad * 8);

  // staging: thread owns rows {rs0, rs0+32}, chunk col8; swizzled slot col8^(row&7)
  const int rs0 = tid >> 3, rs1 = rs0 + 32;
  const int col8 = tid & 7;
  const int so = (col8 ^ (rs0 & 7)) * 8;         // swizzled u16 offset within row
  const int o0 = col8 * 8;                       // global col offset
  // lane-constant swizzled chunk offsets for all frag reads (chunks quad and 4+quad)
  const int x0 = (quad ^ (l16 & 7)) * 8;
  const int x1 = ((4 + quad) ^ (l16 & 7)) * 8;
  const u16* ksrc = qkv + 2048 + g * HD_;        // row stride LDQ
  const u16* vsrc = vT + (size_t)g * HD_ * S_LEN;// row stride S_LEN

  ushort8 kp0, kp1, vp0, vp1;
  auto gload = [&](int t) {                      // tile t -> regs
    const int tb = t * 64;
    kp0 = *(const ushort8*)(ksrc + (size_t)(tb + rs0) * LDQ + o0);
    kp1 = *(const ushort8*)(ksrc + (size_t)(tb + rs1) * LDQ + o0);
    vp0 = *(const ushort8*)(vsrc + (size_t)rs0 * S_LEN + tb + o0);
    vp1 = *(const ushort8*)(vsrc + (size_t)rs1 * S_LEN + tb + o0);
  };
  auto tile_of = [&](int i) { return (i <= p_) ? i : (i - p_ - 1); };

  u16* myP = &pS[wave][0];
  int pp = 0;

  // prologue: stage tile 0 -> buf0; prefetch tile_of(1) -> regs
  gload(0);
  *(ushort8*)&Ks[0][rs0 * 64 + so] = kp0;
  *(ushort8*)&Ks[0][rs1 * 64 + so] = kp1;
  *(ushort8*)&Vs[0][rs0 * 64 + so] = vp0;
  *(ushort8*)&Vs[0][rs1 * 64 + so] = vp1;
  gload(tile_of(1));
  __syncthreads();

  auto phase = [&](int qt, int qg, bf16x8 q0, bf16x8 q1, int ibase) {
    floatx4 O[4] = {};                           // O^T: row=hd(nt*16+quad*4+r), col=q(l16)
    floatx4 lac = {};                            // l via MFMA ones-row
    for (int kt = 0; kt <= qt; kt++) {
      const int i = ibase + kt;                  // global iter 0..32
      const u16* Kc = &Ks[pp][0];
      const u16* Vc = &Vs[pp][0];

      // ---- K frags from current buffer ----
      bf16x8 kf[4][2];
#pragma unroll
      for (int sub = 0; sub < 4; sub++) {
        const u16* kb = Kc + (sub * 16 + l16) * 64;
        kf[sub][0] = ld8(kb + x0);
        kf[sub][1] = ld8(kb + x1);
      }
      // ---- stage next tile into buf pp^1; prefetch tile after next ----
      if (i < 32) {
        *(ushort8*)&Ks[pp ^ 1][rs0 * 64 + so] = kp0;
        *(ushort8*)&Ks[pp ^ 1][rs1 * 64 + so] = kp1;
        *(ushort8*)&Vs[pp ^ 1][rs0 * 64 + so] = vp0;
        *(ushort8*)&Vs[pp ^ 1][rs1 * 64 + so] = vp1;
        if (i < 31) gload(tile_of(i + 2));
      }
      // ---- S^T = K*Q^T : 4 sub-tiles of 16 keys ----
      floatx4 sf[4];
#pragma unroll
      for (int sub = 0; sub < 4; sub++) {
        floatx4 s = {};
        s = mfma16(kf[sub][0], q0, s);           // A-frag: m=key, k=hd
        s = mfma16(kf[sub][1], q1, s);
        sf[sub] = s;
      }
      if (kt == qt) {                            // diagonal tile: mask key > q
#pragma unroll
        for (int sub = 0; sub < 4; sub++)
#pragma unroll
          for (int r = 0; r < 4; r++)
            if (kt * 64 + sub * 16 + quad * 4 + r > qg) sf[sub][r] = -INFINITY;
      }
      // ---- P = exp2(s'), pack to bf16 pairs ----
      u32x2 pk[4];
#pragma unroll
      for (int sub = 0; sub < 4; sub++) {
        pk[sub].x = pk2bf(__builtin_amdgcn_exp2f(sf[sub][0]), __builtin_amdgcn_exp2f(sf[sub][1]));
        pk[sub].y = pk2bf(__builtin_amdgcn_exp2f(sf[sub][2]), __builtin_amdgcn_exp2f(sf[sub][3]));
      }
      // ---- V frags from current buffer ----
      bf16x8 vf[4][2];
#pragma unroll
      for (int nt = 0; nt < 4; nt++) {
        const u16* vb = Vc + (nt * 16 + l16) * 64;
        vf[nt][0] = ld8(vb + x0);
        vf[nt][1] = ld8(vb + x1);
      }
      // ---- P^T to per-wave LDS scratch (swizzled b64 stores) ----
#pragma unroll
      for (int sub = 0; sub < 4; sub++) {
        const int slot = (2 * sub + (quad >> 1)) ^ (l16 & 7);
        *(u32x2*)&myP[l16 * 64 + slot * 8 + (quad & 1) * 4] = pk[sub];
      }
      asm volatile("s_waitcnt lgkmcnt(0)" ::: "memory");  // wave-local LDS write->read fence
      bf16x8 pf0 = ld8(&myP[l16 * 64 + x0]);     // B-frag: n=q, k=key 0..31
      bf16x8 pf1 = ld8(&myP[l16 * 64 + x1]);     //                key 32..63
      // ---- O^T += V^T * P^T ; l += ones * P^T (matrix pipe) ----
#pragma unroll
      for (int nt = 0; nt < 4; nt++) {
        O[nt] = mfma16(vf[nt][0], pf0, O[nt]);
        O[nt] = mfma16(vf[nt][1], pf1, O[nt]);
      }
      lac = mfma16(onesA, pf0, lac);
      lac = mfma16(onesA, pf1, lac);

      if (i < 32) {
        // LDS must be drained before waves cross (staging visibility); the prefetch
        // global_loads are register-destined and stay IN FLIGHT across the barrier.
        asm volatile("s_waitcnt lgkmcnt(0)" ::: "memory");
        __builtin_amdgcn_s_barrier();
        pp ^= 1;
      }
    }
    const float inv = 1.0f / lac[0];
    const size_t ooff = (size_t)qg * 2048 + h * HD_;
#pragma unroll
    for (int nt = 0; nt < 4; nt++)
#pragma unroll
      for (int r = 0; r < 4; r++)
        o[ooff + nt * 16 + quad * 4 + r] = f2bf(O[nt][r] * inv);
  };

  phase(p_, qgA, qfA0, qfA1, 0);                 // q-tile p_   (kt = 0..p_)
  phase(qtB, qgB, qfB0, qfB1, p_ + 1);           // q-tile 31-p_ (kt = 0..31-p_)
}

extern "C" void kernel_launch(void* const* d_in, const int* in_sizes, int n_in,
                              void* d_out, int out_size, void* d_ws, size_t ws_size,
                              hipStream_t stream) {
  const float* x  = (const float*)d_in[0];
  const float* fc = (const float*)d_in[1];
  const float* wq = (const float*)d_in[2];
  const float* wk = (const float*)d_in[3];
  const float* wv = (const float*)d_in[4];
  const float* wo = (const float*)d_in[5];
  float* out = (float*)d_out;

  // Workspace (30 MB). Lifetimes:
  //   [0,12)MB  qkv bf16: 2048 x 3072 (q|k|v), written by QKV gemm, read-only after rope
  //   [12,24)MB wb bf16: wq|wk|wv (3072 x 2048) — dead after QKV gemm
  //   [12,14)MB vT bf16 (after wb dead)
  //   [14,22)MB wob bf16 (cvt'd after QKV gemm)
  //   [22,30)MB ob bf16: attention output
  // x bf16 (8 MB) lives in d_out (16.8 MB) — overwritten by the final O-GEMM.
  char* ws = (char*)d_ws;
  const size_t MB = 1024 * 1024;
  u16* qkv = (u16*)(ws);
  u16* wb  = (u16*)(ws + 12 * MB);
  u16* vTb = (u16*)(ws + 12 * MB);
  u16* wob = (u16*)(ws + 14 * MB);
  u16* ob  = (u16*)(ws + 22 * MB);
  u16* xb  = (u16*)d_out;
  (void)ws_size; (void)n_in; (void)in_sizes; (void)out_size;

  // 1) x, wq|wk|wv -> bf16
  cvt_kernel<<<4096, 256, 0, stream>>>(x,  xb, 1048576);
  cvt_kernel<<<4096, 256, 0, stream>>>(wq, wb, 1048576);
  cvt_kernel<<<1024, 256, 0, stream>>>(wk, wb + (size_t)2048 * 2048, 262144);
  cvt_kernel<<<1024, 256, 0, stream>>>(wv, wb + (size_t)2560 * 2048, 262144);
  // 2) fused QKV projection (128x96 tile -> 512 blocks = 2/CU, global_load_lds staging)
  gemm_db<128, 96, 1><<<dim3(32, 16), 256, 0, stream>>>(xb, wb, qkv, LDQ, 2048, 2048);
  // 3) wo -> bf16 (wb region dead now)
  cvt_kernel<<<4096, 256, 0, stream>>>(wo, wob, 1048576);
  // 4) RoPE: q pre-scaled by log2e/sqrt(HD); k unscaled
  rope_kernel<<<8192, 256, 0, stream>>>(qkv, fc, 5, LDQ, 0.18033688f);
  rope_kernel<<<2048, 256, 0, stream>>>(qkv + 2048, fc, 3, LDQ, 1.0f);
  // 5) V transpose
  transpose_v<<<4096, 256, 0, stream>>>(qkv, vTb);
  // 6) causal GQA flash attention -> ob (512 uniform 33-iter blocks, two-phase)
  attn_kernel<<<dim3(NH, 16), 256, 0, stream>>>(qkv, vTb, ob);
  // 7) output projection (128x64 tile -> 512 blocks, fp32 out, gload_lds) — overwrites xb
  gemm_db<128, 64, 0><<<dim3(32, 16), 256, 0, stream>>>(ob, wob, out, 2048, 2048, 2048);
}

// Round 9
// 227.099 us; speedup vs baseline: 1.0190x; 1.0190x over previous
//
#include <hip/hip_runtime.h>

typedef unsigned short u16;
typedef unsigned int u32;
typedef __bf16 bf16x8 __attribute__((ext_vector_type(8)));
typedef unsigned short ushort8 __attribute__((ext_vector_type(8)));
typedef float floatx4 __attribute__((ext_vector_type(4)));
typedef u32 u32x2 __attribute__((ext_vector_type(2)));

#define S_LEN 2048
#define NH 32
#define NKV 8
#define HD_ 64
#define LDQ 3072   // qkv row stride: [q 0..2047 | k 2048..2559 | v 2560..3071]

__device__ __forceinline__ u16 f2bf(float f) {
  unsigned u = __builtin_bit_cast(unsigned, f);
  u += 0x7FFF + ((u >> 16) & 1);   // round-to-nearest-even
  return (u16)(u >> 16);
}
__device__ __forceinline__ float bf2f(u16 h) {
  unsigned u = ((unsigned)h) << 16;
  return __builtin_bit_cast(float, u);
}
__device__ __forceinline__ bf16x8 ld8(const u16* p) {
  return __builtin_bit_cast(bf16x8, *(const ushort8*)p);
}
__device__ __forceinline__ floatx4 mfma16(bf16x8 a, bf16x8 b, floatx4 c) {
  return __builtin_amdgcn_mfma_f32_16x16x32_bf16(a, b, c, 0, 0, 0);
}
// two fp32 -> packed bf16 pair (round-half-up via +0x8000, then byte-perm)
__device__ __forceinline__ u32 pk2bf(float a, float b) {
  u32 ua = __builtin_bit_cast(u32, a) + 0x8000u;
  u32 ub = __builtin_bit_cast(u32, b) + 0x8000u;
  return __builtin_amdgcn_perm(ub, ua, 0x07060302);   // [bf(a) | bf(b)<<16]
}

// ---------------- fp32 -> bf16 convert (vectorized) ----------------
// r9 note: the r7/r8 fused cvt4/mid kernels crashed deterministically (GPU fault
// signature) despite clean static bounds audits — fusion abandoned; back to the
// r5-proven separate kernels.
__global__ void cvt_kernel(const float* __restrict__ in, u16* __restrict__ out, int n4) {
  int i = blockIdx.x * blockDim.x + threadIdx.x;
  if (i >= n4) return;
  float4 v = ((const float4*)in)[i];
  ((ushort4*)out)[i] = make_ushort4(f2bf(v.x), f2bf(v.y), f2bf(v.z), f2bf(v.w));
}

// ---------------- Double-buffered GEMM: C[M][N] = A[M][K] @ B[N][K]^T (bf16 in) ------------
// TM x TN tile, BK=64, 4 waves (2x2). Single barrier per K-iter. LDS chunk-XOR swizzle:
// conflict-free (measured 0). REG-STAGED on purpose (r6 lesson): global->reg prefetch is
// issued TWO iterations ahead (~3.4Kcy of cover, HBM ~900cy fully hidden); r6's
// global_load_lds DMA had only one compute phase of cover before the barrier's vmcnt(0)
// drain and regressed 45.6 -> 50.7us. Tiles r3-proven: QKV 128x96 (2/CU), O-proj 128x64.
// r9: XCD-aware block swizzle (T1). FETCH_SIZE was 39MB vs 20MB unique inputs (~2x HBM
// over-fetch) because round-robin dispatch spreads panel-sharing blocks across all 8
// per-XCD L2s. Both grids are 512 blocks = 64/XCD exactly; chunked remap is bijective.
// Col-major decomposition: each XCD owns 4 contiguous B col-panels (L2-resident) and
// sweeps A in K-lockstep across its 64 co-resident blocks.
template <int TM, int TN, int OUT_BF16>
__global__ __launch_bounds__(256) void gemm_db(
    const u16* __restrict__ A, const u16* __restrict__ B, void* __restrict__ C,
    int ldc, int K, int lda) {
  __shared__ __align__(16) u16 As[2][TM * 64];
  __shared__ __align__(16) u16 Bs[2][TN * 64];
  const int tid = threadIdx.x;
  const int wave = tid >> 6, lane = tid & 63;
  const int quad = lane >> 4, l16 = lane & 15;
  // XCD-chunked bijective remap (requires nwg % 8 == 0; both call sites are 512 blocks).
  // Dispatch id lin0 = by*gridDim.x+bx round-robins XCDs; lin0&7 IS the XCD. Remap so
  // each XCD gets a contiguous chunk, decomposed col-major (bx slow over the chunk).
  const int nwg = gridDim.x * gridDim.y;
  int lin = (int)blockIdx.y * gridDim.x + blockIdx.x;
  lin = (lin & 7) * (nwg >> 3) + (lin >> 3);
  const int bm = (lin % gridDim.y) * TM, bn = (lin / gridDim.y) * TN;
  const int wr = (wave >> 1) * (TM / 2), wc = (wave & 1) * (TN / 2);
  constexpr int MI = TM / 32, NI = TN / 32;
  const int crow = tid >> 3, col8 = tid & 7;     // staging: row base, 8-elem col chunk

  size_t aoff[MI], boff[NI];
#pragma unroll
  for (int j = 0; j < MI; j++) aoff[j] = (size_t)(bm + crow + j * 32) * lda + col8 * 8;
#pragma unroll
  for (int j = 0; j < NI; j++) boff[j] = (size_t)(bn + crow + j * 32) * K + col8 * 8;

  ushort8 a8[MI], b8[NI];
  auto load_tiles = [&](int k0) {
#pragma unroll
    for (int j = 0; j < MI; j++) a8[j] = *(const ushort8*)(A + aoff[j] + k0);
#pragma unroll
    for (int j = 0; j < NI; j++) b8[j] = *(const ushort8*)(B + boff[j] + k0);
  };
  auto write_tiles = [&](int p) {
#pragma unroll
    for (int j = 0; j < MI; j++) {
      const int row = crow + j * 32;
      *(ushort8*)&As[p][row * 64 + ((col8 ^ (row & 7)) * 8)] = a8[j];
    }
#pragma unroll
    for (int j = 0; j < NI; j++) {
      const int row = crow + j * 32;
      *(ushort8*)&Bs[p][row * 64 + ((col8 ^ (row & 7)) * 8)] = b8[j];
    }
  };

  floatx4 acc[MI][NI] = {};
  load_tiles(0);
  write_tiles(0);
  __syncthreads();
  int p = 0;
  for (int k0 = 0; k0 < K; k0 += 64) {
    const bool more = (k0 + 64 < K);
    if (more) load_tiles(k0 + 64);               // prefetch next tile (covered by compute)
#pragma unroll
    for (int kh = 0; kh < 2; kh++) {
      bf16x8 af[MI], bfr[NI];
#pragma unroll
      for (int mi = 0; mi < MI; mi++) {
        const int row = wr + mi * 16 + l16;
        af[mi] = ld8(&As[p][row * 64 + (((kh * 4 + quad) ^ (row & 7)) * 8)]);
      }
#pragma unroll
      for (int ni = 0; ni < NI; ni++) {
        const int row = wc + ni * 16 + l16;
        bfr[ni] = ld8(&Bs[p][row * 64 + (((kh * 4 + quad) ^ (row & 7)) * 8)]);
      }
#pragma unroll
      for (int mi = 0; mi < MI; mi++)
#pragma unroll
        for (int ni = 0; ni < NI; ni++)
          acc[mi][ni] = mfma16(af[mi], bfr[ni], acc[mi][ni]);
    }
    if (more) {
      write_tiles(p ^ 1);                        // vmcnt wait lands here, post-compute
      __syncthreads();                           // one barrier per iter
      p ^= 1;
    }
  }

#pragma unroll
  for (int mi = 0; mi < MI; mi++)
#pragma unroll
    for (int ni = 0; ni < NI; ni++)
#pragma unroll
      for (int r = 0; r < 4; r++) {
        const int row = bm + wr + mi * 16 + quad * 4 + r;   // C/D: row=(lane>>4)*4+reg
        const int col = bn + wc + ni * 16 + l16;            //      col=lane&15
        if (OUT_BF16) ((u16*)C)[(size_t)row * ldc + col] = f2bf(acc[mi][ni][r]);
        else          ((float*)C)[(size_t)row * ldc + col] = acc[mi][ni][r];
      }
}

// ---------------- RoPE in-place on bf16, rows of `row_stride`, nheads = 1<<h_bits ----------------
__global__ void rope_kernel(u16* __restrict__ qk, const float* __restrict__ fc, int h_bits,
                            int row_stride, float scale) {
  int idx = blockIdx.x * blockDim.x + threadIdx.x;   // over S * nheads * 32 pairs
  int d = idx & 31;
  int t = idx >> 5;
  int hh = t & ((1 << h_bits) - 1);
  int s = t >> h_bits;
  float c  = fc[s * 64 + d * 2];
  float sn = fc[s * 64 + d * 2 + 1];
  size_t base = (size_t)s * row_stride + hh * 64 + d * 2;
  float x0 = bf2f(qk[base]), x1 = bf2f(qk[base + 1]);
  qk[base]     = f2bf((x0 * c - x1 * sn) * scale);
  qk[base + 1] = f2bf((x0 * sn + x1 * c) * scale);
}

// ---------------- V transpose: qkv[s][2560 + g*64+hd] -> vT[(g*64+hd)][s] ----------------
__global__ void transpose_v(const u16* __restrict__ qkv, u16* __restrict__ vT) {
  int idx = blockIdx.x * blockDim.x + threadIdx.x;   // over KV*HD*S
  int s = idx & (S_LEN - 1);
  int t = idx >> 11;                                 // g*64+hd
  vT[idx] = qkv[(size_t)s * LDQ + 2560 + t];
}

// ---------------- Flash attention (causal, GQA) — r5 structure (measured best) ------------
// r2's two-phase uniform schedule (block (h,p) runs q-tiles p then 31-p, exactly 33 iters
// per block) + r3's conflict-free chunk-XOR stride-64 LDS + K/V double-buffer with ONE RAW
// s_barrier per iter (lgkmcnt(0) only; prefetch global_loads are register-destined and
// stay in flight across the barrier).
__global__ __launch_bounds__(256) void attn_kernel(const u16* qkv, const u16* __restrict__ vT,
                                                   u16* __restrict__ o) {
  __shared__ __align__(16) u16 Ks[2][64 * 64];   // [key][hd], chunk-XOR swizzled
  __shared__ __align__(16) u16 Vs[2][64 * 64];   // [hd][key], chunk-XOR swizzled
  __shared__ __align__(16) u16 pS[4][16 * 64];   // per-wave P^T scratch (reused A/B)
  const int h = blockIdx.x;
  const int g = h >> 2;                          // kv head
  const int tid = threadIdx.x;
  const int wave = tid >> 6, lane = tid & 63;
  const int quad = lane >> 4, l16 = lane & 15;
  const int p_ = (int)blockIdx.y;                // 0..15
  const int qtB = 31 - p_;                       // pair (p_, 31-p_): 33 iters total

  const ushort8 ones_u = {0x3F80, 0x3F80, 0x3F80, 0x3F80, 0x3F80, 0x3F80, 0x3F80, 0x3F80};
  const bf16x8 onesA = __builtin_bit_cast(bf16x8, ones_u);

  const int qrow = wave * 16 + l16;
  const int qgA = p_ * 64 + qrow, qgB = qtB * 64 + qrow;
  const size_t qoffA = (size_t)qgA * LDQ + h * HD_;
  const size_t qoffB = (size_t)qgB * LDQ + h * HD_;
  bf16x8 qfA0 = ld8(qkv + qoffA + quad * 8);     // B-frag: n=q, k=hd (pre-scaled log2e/8)
  bf16x8 qfA1 = ld8(qkv + qoffA + 32 + quad * 8);
  bf16x8 qfB0 = ld8(qkv + qoffB + quad * 8);
  bf16x8 qfB1 = ld8(qkv + qoffB + 32 + quad * 8);

  // staging: thread owns rows {rs0, rs0+32}, chunk col8; swizzled slot col8^(row&7)
  const int rs0 = tid >> 3, rs1 = rs0 + 32;
  const int col8 = tid & 7;
  const int so = (col8 ^ (rs0 & 7)) * 8;         // swizzled u16 offset within row
  const int o0 = col8 * 8;                       // global col offset
  // lane-constant swizzled chunk offsets for all frag reads (chunks quad and 4+quad)
  const int x0 = (quad ^ (l16 & 7)) * 8;
  const int x1 = ((4 + quad) ^ (l16 & 7)) * 8;
  const u16* ksrc = qkv + 2048 + g * HD_;        // row stride LDQ
  const u16* vsrc = vT + (size_t)g * HD_ * S_LEN;// row stride S_LEN

  ushort8 kp0, kp1, vp0, vp1;
  auto gload = [&](int t) {                      // tile t -> regs
    const int tb = t * 64;
    kp0 = *(const ushort8*)(ksrc + (size_t)(tb + rs0) * LDQ + o0);
    kp1 = *(const ushort8*)(ksrc + (size_t)(tb + rs1) * LDQ + o0);
    vp0 = *(const ushort8*)(vsrc + (size_t)rs0 * S_LEN + tb + o0);
    vp1 = *(const ushort8*)(vsrc + (size_t)rs1 * S_LEN + tb + o0);
  };
  auto tile_of = [&](int i) { return (i <= p_) ? i : (i - p_ - 1); };

  u16* myP = &pS[wave][0];
  int pp = 0;

  // prologue: stage tile 0 -> buf0; prefetch tile_of(1) -> regs
  gload(0);
  *(ushort8*)&Ks[0][rs0 * 64 + so] = kp0;
  *(ushort8*)&Ks[0][rs1 * 64 + so] = kp1;
  *(ushort8*)&Vs[0][rs0 * 64 + so] = vp0;
  *(ushort8*)&Vs[0][rs1 * 64 + so] = vp1;
  gload(tile_of(1));
  __syncthreads();

  auto phase = [&](int qt, int qg, bf16x8 q0, bf16x8 q1, int ibase) {
    floatx4 O[4] = {};                           // O^T: row=hd(nt*16+quad*4+r), col=q(l16)
    floatx4 lac = {};                            // l via MFMA ones-row
    for (int kt = 0; kt <= qt; kt++) {
      const int i = ibase + kt;                  // global iter 0..32
      const u16* Kc = &Ks[pp][0];
      const u16* Vc = &Vs[pp][0];

      // ---- K frags from current buffer ----
      bf16x8 kf[4][2];
#pragma unroll
      for (int sub = 0; sub < 4; sub++) {
        const u16* kb = Kc + (sub * 16 + l16) * 64;
        kf[sub][0] = ld8(kb + x0);
        kf[sub][1] = ld8(kb + x1);
      }
      // ---- stage next tile into buf pp^1; prefetch tile after next ----
      if (i < 32) {
        *(ushort8*)&Ks[pp ^ 1][rs0 * 64 + so] = kp0;
        *(ushort8*)&Ks[pp ^ 1][rs1 * 64 + so] = kp1;
        *(ushort8*)&Vs[pp ^ 1][rs0 * 64 + so] = vp0;
        *(ushort8*)&Vs[pp ^ 1][rs1 * 64 + so] = vp1;
        if (i < 31) gload(tile_of(i + 2));
      }
      // ---- S^T = K*Q^T : 4 sub-tiles of 16 keys ----
      floatx4 sf[4];
#pragma unroll
      for (int sub = 0; sub < 4; sub++) {
        floatx4 s = {};
        s = mfma16(kf[sub][0], q0, s);           // A-frag: m=key, k=hd
        s = mfma16(kf[sub][1], q1, s);
        sf[sub] = s;
      }
      if (kt == qt) {                            // diagonal tile: mask key > q
#pragma unroll
        for (int sub = 0; sub < 4; sub++)
#pragma unroll
          for (int r = 0; r < 4; r++)
            if (kt * 64 + sub * 16 + quad * 4 + r > qg) sf[sub][r] = -INFINITY;
      }
      // ---- P = exp2(s'), pack to bf16 pairs ----
      u32x2 pk[4];
#pragma unroll
      for (int sub = 0; sub < 4; sub++) {
        pk[sub].x = pk2bf(__builtin_amdgcn_exp2f(sf[sub][0]), __builtin_amdgcn_exp2f(sf[sub][1]));
        pk[sub].y = pk2bf(__builtin_amdgcn_exp2f(sf[sub][2]), __builtin_amdgcn_exp2f(sf[sub][3]));
      }
      // ---- V frags from current buffer ----
      bf16x8 vf[4][2];
#pragma unroll
      for (int nt = 0; nt < 4; nt++) {
        const u16* vb = Vc + (nt * 16 + l16) * 64;
        vf[nt][0] = ld8(vb + x0);
        vf[nt][1] = ld8(vb + x1);
      }
      // ---- P^T to per-wave LDS scratch (swizzled b64 stores) ----
#pragma unroll
      for (int sub = 0; sub < 4; sub++) {
        const int slot = (2 * sub + (quad >> 1)) ^ (l16 & 7);
        *(u32x2*)&myP[l16 * 64 + slot * 8 + (quad & 1) * 4] = pk[sub];
      }
      asm volatile("s_waitcnt lgkmcnt(0)" ::: "memory");  // wave-local LDS write->read fence
      bf16x8 pf0 = ld8(&myP[l16 * 64 + x0]);     // B-frag: n=q, k=key 0..31
      bf16x8 pf1 = ld8(&myP[l16 * 64 + x1]);     //                key 32..63
      // ---- O^T += V^T * P^T ; l += ones * P^T (matrix pipe) ----
#pragma unroll
      for (int nt = 0; nt < 4; nt++) {
        O[nt] = mfma16(vf[nt][0], pf0, O[nt]);
        O[nt] = mfma16(vf[nt][1], pf1, O[nt]);
      }
      lac = mfma16(onesA, pf0, lac);
      lac = mfma16(onesA, pf1, lac);

      if (i < 32) {
        // LDS must be drained before waves cross (staging visibility); the prefetch
        // global_loads are register-destined and stay IN FLIGHT across the barrier.
        asm volatile("s_waitcnt lgkmcnt(0)" ::: "memory");
        __builtin_amdgcn_s_barrier();
        pp ^= 1;
      }
    }
    const float inv = 1.0f / lac[0];
    const size_t ooff = (size_t)qg * 2048 + h * HD_;
#pragma unroll
    for (int nt = 0; nt < 4; nt++)
#pragma unroll
      for (int r = 0; r < 4; r++)
        o[ooff + nt * 16 + quad * 4 + r] = f2bf(O[nt][r] * inv);
  };

  phase(p_, qgA, qfA0, qfA1, 0);                 // q-tile p_   (kt = 0..p_)
  phase(qtB, qgB, qfB0, qfB1, p_ + 1);           // q-tile 31-p_ (kt = 0..31-p_)
}

extern "C" void kernel_launch(void* const* d_in, const int* in_sizes, int n_in,
                              void* d_out, int out_size, void* d_ws, size_t ws_size,
                              hipStream_t stream) {
  const float* x  = (const float*)d_in[0];
  const float* fc = (const float*)d_in[1];
  const float* wq = (const float*)d_in[2];
  const float* wk = (const float*)d_in[3];
  const float* wv = (const float*)d_in[4];
  const float* wo = (const float*)d_in[5];
  float* out = (float*)d_out;

  // Workspace (30 MB). Lifetimes:
  //   [0,12)MB  qkv bf16: 2048 x 3072 (q|k|v), written by QKV gemm, read-only after rope
  //   [12,24)MB wb bf16: wq|wk|wv (3072 x 2048) — dead after QKV gemm
  //   [12,14)MB vT bf16 (after wb dead)
  //   [14,22)MB wob bf16 (cvt'd after QKV gemm)
  //   [22,30)MB ob bf16: attention output
  // x bf16 (8 MB) lives in d_out (16.8 MB) — overwritten by the final O-GEMM.
  char* ws = (char*)d_ws;
  const size_t MB = 1024 * 1024;
  u16* qkv = (u16*)(ws);
  u16* wb  = (u16*)(ws + 12 * MB);
  u16* vTb = (u16*)(ws + 12 * MB);
  u16* wob = (u16*)(ws + 14 * MB);
  u16* ob  = (u16*)(ws + 22 * MB);
  u16* xb  = (u16*)d_out;
  (void)ws_size; (void)n_in; (void)in_sizes; (void)out_size;

  // 1) x, wq|wk|wv -> bf16
  cvt_kernel<<<4096, 256, 0, stream>>>(x,  xb, 1048576);
  cvt_kernel<<<4096, 256, 0, stream>>>(wq, wb, 1048576);
  cvt_kernel<<<1024, 256, 0, stream>>>(wk, wb + (size_t)2048 * 2048, 262144);
  cvt_kernel<<<1024, 256, 0, stream>>>(wv, wb + (size_t)2560 * 2048, 262144);
  // 2) fused QKV projection (128x96 tile -> 512 blocks = 2/CU, reg-staged dbuf, XCD swizzle)
  gemm_db<128, 96, 1><<<dim3(32, 16), 256, 0, stream>>>(xb, wb, qkv, LDQ, 2048, 2048);
  // 3) wo -> bf16 (wb region dead now)
  cvt_kernel<<<4096, 256, 0, stream>>>(wo, wob, 1048576);
  // 4) RoPE: q pre-scaled by log2e/sqrt(HD); k unscaled
  rope_kernel<<<8192, 256, 0, stream>>>(qkv, fc, 5, LDQ, 0.18033688f);
  rope_kernel<<<2048, 256, 0, stream>>>(qkv + 2048, fc, 3, LDQ, 1.0f);
  // 5) V transpose
  transpose_v<<<4096, 256, 0, stream>>>(qkv, vTb);
  // 6) causal GQA flash attention -> ob (512 uniform 33-iter blocks, two-phase)
  attn_kernel<<<dim3(NH, 16), 256, 0, stream>>>(qkv, vTb, ob);
  // 7) output projection (128x64 tile -> 512 blocks, fp32 out, XCD swizzle) — overwrites xb
  gemm_db<128, 64, 0><<<dim3(32, 16), 256, 0, stream>>>(ob, wob, out, 2048, 2048, 2048);
}